// Round 1
// baseline (1033.301 us; speedup 1.0000x reference)
//
#include <hip/hip_runtime.h>
#include <hip/hip_bf16.h>
#include <cstdint>

// Problem constants: B=4, S=2048, D=1024, H=16, HD=64
static constexpr int Bq  = 4;
static constexpr int Sq  = 2048;
static constexpr int Dq  = 1024;
static constexpr int Hq  = 16;
static constexpr int HDq = 64;
static constexpr int ROWS = Bq * Sq;        // 8192
static constexpr int QKV_N = 3 * Dq;        // 3072

typedef __bf16 bf16x8 __attribute__((ext_vector_type(8)));
typedef __bf16 bf16x4 __attribute__((ext_vector_type(4)));
typedef float  floatx4 __attribute__((ext_vector_type(4)));

#define MFMA16(a, b, c) __builtin_amdgcn_mfma_f32_16x16x32_bf16((a), (b), (c), 0, 0, 0)

// ---------------------------------------------------------------------------
// fp32 -> bf16 elementwise convert, 4 elems/thread
__global__ __launch_bounds__(256) void cvt4_kernel(const float4* __restrict__ in,
                                                   bf16x4* __restrict__ out, int n4) {
    int i = blockIdx.x * 256 + threadIdx.x;
    if (i < n4) {
        float4 v = in[i];
        bf16x4 o;
        o[0] = (__bf16)v.x; o[1] = (__bf16)v.y; o[2] = (__bf16)v.z; o[3] = (__bf16)v.w;
        out[i] = o;
    }
}

// fp32 [K,N] -> bf16 transposed [N,K], LDS-tiled 32x32 for coalescing
__global__ __launch_bounds__(256) void tcvt_kernel(const float* __restrict__ in,
                                                   __bf16* __restrict__ out, int K, int N) {
    __shared__ float t[32][33];
    int n0 = blockIdx.x * 32, k0 = blockIdx.y * 32;
    int c = threadIdx.x & 31, r0 = threadIdx.x >> 5;  // 8 rows per pass
#pragma unroll
    for (int rr = 0; rr < 32; rr += 8)
        t[r0 + rr][c] = in[(size_t)(k0 + r0 + rr) * N + n0 + c];
    __syncthreads();
#pragma unroll
    for (int rr = 0; rr < 32; rr += 8)
        out[(size_t)(n0 + r0 + rr) * K + k0 + c] = (__bf16)t[c][r0 + rr];
}

// ---------------------------------------------------------------------------
// C[M,N] = A[M,K] @ BT[N,K]^T + bias[N].  A,BT bf16 row-major; C bf16 or f32.
// Block: 256 thr = 4 waves; tile 64(M) x 64(N); wave w owns rows w*16..+16.
// Fragments loaded straight from global (B rows shared across waves -> L1).
template <bool OUT_F32>
__global__ __launch_bounds__(256) void gemm_bt_kernel(const __bf16* __restrict__ A,
                                                      const __bf16* __restrict__ BT,
                                                      const float* __restrict__ bias,
                                                      void* __restrict__ Cout,
                                                      int M, int N, int K) {
    const int lane = threadIdx.x & 63;
    const int wave = threadIdx.x >> 6;
    const int m0 = blockIdx.y * 64 + wave * 16;
    const int n0 = blockIdx.x * 64;
    const int l15 = lane & 15;
    const int kg = (lane >> 4) * 8;  // k-subgroup for A/B fragments

    const __bf16* arow = A + (size_t)(m0 + l15) * K + kg;
    floatx4 acc[4] = {};
    for (int k0 = 0; k0 < K; k0 += 32) {
        bf16x8 a = *(const bf16x8*)(arow + k0);
#pragma unroll
        for (int t = 0; t < 4; ++t) {
            const __bf16* brow = BT + (size_t)(n0 + t * 16 + l15) * K + k0 + kg;
            bf16x8 b = *(const bf16x8*)brow;
            acc[t] = MFMA16(a, b, acc[t]);
        }
    }
    // C/D layout: col = lane&15, row = (lane>>4)*4 + reg   [verified m89/m91]
    const int r0 = (lane >> 4) * 4;
#pragma unroll
    for (int t = 0; t < 4; ++t) {
        int col = n0 + t * 16 + l15;
        float bv = bias[col];
#pragma unroll
        for (int i = 0; i < 4; ++i) {
            size_t off = (size_t)(m0 + r0 + i) * N + col;
            float v = acc[t][i] + bv;
            if (OUT_F32) ((float*)Cout)[off] = v;
            else         ((__bf16*)Cout)[off] = (__bf16)v;
        }
    }
}

// ---------------------------------------------------------------------------
// Flash attention over qkv[8192,3072] bf16. Per head h, row r of qkv holds
// q = [h*192, +64), k = [h*192+64, +64), v = [h*192+128, +64).
// Block: one (b,h), 64 q-rows; 4 waves, wave w owns q rows w*16..+16.
// Writes attention output in the reference's quirk reshape layout:
//   v2[b*2048 + h*128 + s/16][(s%16)*64 + hd]
__global__ __launch_bounds__(256) void attn_kernel(const __bf16* __restrict__ qkv,
                                                   __bf16* __restrict__ v2) {
    const int bh = blockIdx.y;
    const int b = bh >> 4, h = bh & 15;
    const int q0 = blockIdx.x * 64;
    const int lane = threadIdx.x & 63;
    const int wave = threadIdx.x >> 6;
    const int l15 = lane & 15;
    const int kg = (lane >> 4) * 8;
    const size_t rs = QKV_N;  // 3072
    const __bf16* base = qkv + (size_t)b * Sq * rs + (size_t)h * (3 * HDq);

    __shared__ __bf16 VT[64][72];  // V^T tile: [d][key], 72*2B=144B row = 16B-multiple
    __shared__ __bf16 P[64][72];   // P tile (C-layout -> A-layout roundtrip)

    // Q fragments live in registers for the whole kernel.
    // A-frag layout: A[m=lane&15][k=(lane>>4)*8+j]
    const int qrow = q0 + wave * 16 + l15;
    bf16x8 qa0 = *(const bf16x8*)(base + (size_t)qrow * rs + kg);
    bf16x8 qa1 = *(const bf16x8*)(base + (size_t)qrow * rs + 32 + kg);

    floatx4 o[4] = {};
    float m_i[4], l_i[4];
#pragma unroll
    for (int i = 0; i < 4; ++i) { m_i[i] = -1e30f; l_i[i] = 0.f; }

    for (int kt = 0; kt < Sq; kt += 64) {
        __syncthreads();  // previous iteration's PV reads of VT are done
        // Stage V^T into LDS: V[key][d] = base[(kt+key)*rs + 128 + d]
#pragma unroll
        for (int it = 0; it < 2; ++it) {
            int key = (threadIdx.x >> 3) + it * 32;
            int dg = (threadIdx.x & 7) * 8;
            bf16x8 vv = *(const bf16x8*)(base + (size_t)(kt + key) * rs + 2 * HDq + dg);
#pragma unroll
            for (int j = 0; j < 8; ++j) VT[dg + j][key] = vv[j];
        }
        __syncthreads();

        // S = Q K^T : B-frag lane holds K[key = n][d = k] -> contiguous rows of K
        floatx4 s[4] = {};
#pragma unroll
        for (int t = 0; t < 4; ++t) {
            const __bf16* krow = base + (size_t)(kt + t * 16 + l15) * rs + HDq;
            bf16x8 b0 = *(const bf16x8*)(krow + kg);
            bf16x8 b1 = *(const bf16x8*)(krow + 32 + kg);
            s[t] = MFMA16(qa0, b0, s[t]);
            s[t] = MFMA16(qa1, b1, s[t]);
        }
#pragma unroll
        for (int t = 0; t < 4; ++t) s[t] *= 0.125f;  // 1/sqrt(64)

        // Row max: per-lane over 4 col-tiles, then across the 16-lane col group
        float mx[4];
#pragma unroll
        for (int i = 0; i < 4; ++i)
            mx[i] = fmaxf(fmaxf(s[0][i], s[1][i]), fmaxf(s[2][i], s[3][i]));
#pragma unroll
        for (int m = 1; m < 16; m <<= 1) {
#pragma unroll
            for (int i = 0; i < 4; ++i) mx[i] = fmaxf(mx[i], __shfl_xor(mx[i], m));
        }

        float alpha[4], rsum[4];
#pragma unroll
        for (int i = 0; i < 4; ++i) {
            float mn = fmaxf(m_i[i], mx[i]);
            alpha[i] = __expf(m_i[i] - mn);
            m_i[i] = mn;
            rsum[i] = 0.f;
        }
#pragma unroll
        for (int t = 0; t < 4; ++t) {
#pragma unroll
            for (int i = 0; i < 4; ++i) {
                float p = __expf(s[t][i] - m_i[i]);
                s[t][i] = p;
                rsum[i] += p;
            }
        }
#pragma unroll
        for (int m = 1; m < 16; m <<= 1) {
#pragma unroll
            for (int i = 0; i < 4; ++i) rsum[i] += __shfl_xor(rsum[i], m);
        }
#pragma unroll
        for (int i = 0; i < 4; ++i) l_i[i] = l_i[i] * alpha[i] + rsum[i];

        // Rescale O and dump P to LDS (wave-local rows: no barrier needed)
#pragma unroll
        for (int t = 0; t < 4; ++t) {
#pragma unroll
            for (int i = 0; i < 4; ++i) {
                o[t][i] *= alpha[i];
                P[wave * 16 + (lane >> 4) * 4 + i][t * 16 + l15] = (__bf16)s[t][i];
            }
        }

        // O += P V : A-frag from P rows (wave-local), B-frag from VT rows
#pragma unroll
        for (int ks = 0; ks < 2; ++ks) {
            bf16x8 pa = *(const bf16x8*)(&P[wave * 16 + l15][ks * 32 + kg]);
#pragma unroll
            for (int t = 0; t < 4; ++t) {
                bf16x8 vb = *(const bf16x8*)(&VT[t * 16 + l15][ks * 32 + kg]);
                o[t] = MFMA16(pa, vb, o[t]);
            }
        }
    }

    // Epilogue: normalize and write in the quirk reshape layout
#pragma unroll
    for (int t = 0; t < 4; ++t) {
#pragma unroll
        for (int i = 0; i < 4; ++i) {
            int q = q0 + wave * 16 + (lane >> 4) * 4 + i;  // global s index
            int d = t * 16 + l15;
            float val = o[t][i] / l_i[i];
            size_t row = (size_t)b * Sq + h * 128 + (q >> 4);
            size_t col = (size_t)(q & 15) * 64 + d;
            v2[row * Dq + col] = (__bf16)val;
        }
    }
}

// ---------------------------------------------------------------------------
extern "C" void kernel_launch(void* const* d_in, const int* in_sizes, int n_in,
                              void* d_out, int out_size, void* d_ws, size_t ws_size,
                              hipStream_t stream) {
    const float* x    = (const float*)d_in[0];  // [4,2048,1024]
    const float* Wqkv = (const float*)d_in[1];  // [1024,3072]
    const float* bqkv = (const float*)d_in[2];  // [3072]
    const float* Wo   = (const float*)d_in[3];  // [1024,1024]
    const float* bo   = (const float*)d_in[4];  // [1024]
    float* out = (float*)d_out;                 // [4,2048,1024] f32

    // Workspace layout (bf16, all 16B-aligned): total ~88 MB
    __bf16* xb    = (__bf16*)d_ws;                        // 8192*1024
    __bf16* WqkvT = xb    + (size_t)ROWS * Dq;            // 3072*1024
    __bf16* WoT   = WqkvT + (size_t)QKV_N * Dq;           // 1024*1024
    __bf16* qkvb  = WoT   + (size_t)Dq * Dq;              // 8192*3072
    __bf16* v2    = qkvb  + (size_t)ROWS * QKV_N;         // 8192*1024

    const int nx4 = ROWS * Dq / 4;
    cvt4_kernel<<<(nx4 + 255) / 256, 256, 0, stream>>>((const float4*)x, (bf16x4*)xb, nx4);
    tcvt_kernel<<<dim3(QKV_N / 32, Dq / 32), 256, 0, stream>>>(Wqkv, WqkvT, Dq, QKV_N);
    tcvt_kernel<<<dim3(Dq / 32, Dq / 32), 256, 0, stream>>>(Wo, WoT, Dq, Dq);

    gemm_bt_kernel<false><<<dim3(QKV_N / 64, ROWS / 64), 256, 0, stream>>>(
        xb, WqkvT, bqkv, (void*)qkvb, ROWS, QKV_N, Dq);

    attn_kernel<<<dim3(Sq / 64, Bq * Hq), 256, 0, stream>>>(qkvb, v2);

    gemm_bt_kernel<true><<<dim3(Dq / 64, ROWS / 64), 256, 0, stream>>>(
        v2, WoT, bo, (void*)out, ROWS, Dq, Dq);
}

// Round 2
// 523.090 us; speedup vs baseline: 1.9754x; 1.9754x over previous
//
#include <hip/hip_runtime.h>
#include <hip/hip_bf16.h>
#include <cstdint>

// Problem constants: B=4, S=2048, D=1024, H=16, HD=64
static constexpr int Bq  = 4;
static constexpr int Sq  = 2048;
static constexpr int Dq  = 1024;
static constexpr int Hq  = 16;
static constexpr int HDq = 64;
static constexpr int ROWS = Bq * Sq;        // 8192
static constexpr int QKV_N = 3 * Dq;        // 3072

typedef __bf16 bf16x8 __attribute__((ext_vector_type(8)));
typedef __bf16 bf16x4 __attribute__((ext_vector_type(4)));
typedef float  floatx4 __attribute__((ext_vector_type(4)));

#define MFMA16(a, b, c) __builtin_amdgcn_mfma_f32_16x16x32_bf16((a), (b), (c), 0, 0, 0)

// Async global->LDS 16B copy (global_load_lds_dwordx4). LDS dest must be
// wave-uniform base + lane*16 — our staging layout is lane-contiguous.
__device__ __forceinline__ void async16(const void* g, void* l) {
    __builtin_amdgcn_global_load_lds(
        (const __attribute__((address_space(1))) uint32_t*)g,
        (__attribute__((address_space(3))) uint32_t*)l, 16, 0, 0);
}

// ---------------------------------------------------------------------------
// fp32 -> bf16 elementwise convert, 4 elems/thread
__global__ __launch_bounds__(256) void cvt4_kernel(const float4* __restrict__ in,
                                                   bf16x4* __restrict__ out, int n4) {
    int i = blockIdx.x * 256 + threadIdx.x;
    if (i < n4) {
        float4 v = in[i];
        bf16x4 o;
        o[0] = (__bf16)v.x; o[1] = (__bf16)v.y; o[2] = (__bf16)v.z; o[3] = (__bf16)v.w;
        out[i] = o;
    }
}

// fp32 [K,N] -> bf16 transposed [N,K], LDS-tiled 32x32 for coalescing
__global__ __launch_bounds__(256) void tcvt_kernel(const float* __restrict__ in,
                                                   __bf16* __restrict__ out, int K, int N) {
    __shared__ float t[32][33];
    int n0 = blockIdx.x * 32, k0 = blockIdx.y * 32;
    int c = threadIdx.x & 31, r0 = threadIdx.x >> 5;  // 8 rows per pass
#pragma unroll
    for (int rr = 0; rr < 32; rr += 8)
        t[r0 + rr][c] = in[(size_t)(k0 + r0 + rr) * N + n0 + c];
    __syncthreads();
#pragma unroll
    for (int rr = 0; rr < 32; rr += 8)
        out[(size_t)(n0 + r0 + rr) * K + k0 + c] = (__bf16)t[c][r0 + rr];
}

// ---------------------------------------------------------------------------
// C[M,N] = A[M,K] @ BT[N,K]^T + bias[N]  (m97-ladder structure).
// 256 thr = 4 waves (2x2); block tile 128(M) x 128(N), BK=32.
// Staging: global_load_lds width=16, lane-contiguous LDS layout (no padding).
// Each wave computes a 64x64 sub-tile = 4x4 MFMA tiles of 16x16x32.
template <bool OUT_F32>
__global__ __launch_bounds__(256) void gemm_bt_kernel(const __bf16* __restrict__ A,
                                                      const __bf16* __restrict__ BT,
                                                      const float* __restrict__ bias,
                                                      void* __restrict__ Cout,
                                                      int M, int N, int K) {
    __shared__ __bf16 As[128 * 32];  // [row][k] row-major, 8 KB
    __shared__ __bf16 Bs[128 * 32];  // [n][k]   row-major, 8 KB

    const int t = threadIdx.x;
    const int lane = t & 63;
    const int wave = t >> 6;
    const int wm = wave & 1, wn = wave >> 1;
    const int l15 = lane & 15;
    const int kg = (lane >> 4) * 8;

    const int m0 = blockIdx.y * 128;
    const int n0 = blockIdx.x * 128;

    // Staging map: issue j covers rows j*64 + t/4, cols (t%4)*8; LDS off = (j*2048 + t*8)
    const int srow = t >> 2;            // 0..63
    const int scol = (t & 3) * 8;
    const __bf16* ag = A  + (size_t)(m0 + srow) * K + scol;
    const __bf16* bg = BT + (size_t)(n0 + srow) * K + scol;
    __bf16* al = As + t * 8;
    __bf16* bl = Bs + t * 8;

    floatx4 acc[4][4] = {};

    for (int k0 = 0; k0 < K; k0 += 32) {
        __syncthreads();  // previous iteration's ds_reads done
        async16(ag + k0,                    al);
        async16(ag + (size_t)64 * K + k0,   al + 2048);
        async16(bg + k0,                    bl);
        async16(bg + (size_t)64 * K + k0,   bl + 2048);
        __syncthreads();  // staging complete (vmcnt drained by barrier)

        bf16x8 af[4], bfr[4];
#pragma unroll
        for (int mi = 0; mi < 4; ++mi)
            af[mi] = *(const bf16x8*)(As + (wm * 64 + mi * 16 + l15) * 32 + kg);
#pragma unroll
        for (int ni = 0; ni < 4; ++ni)
            bfr[ni] = *(const bf16x8*)(Bs + (wn * 64 + ni * 16 + l15) * 32 + kg);
#pragma unroll
        for (int mi = 0; mi < 4; ++mi)
#pragma unroll
            for (int ni = 0; ni < 4; ++ni)
                acc[mi][ni] = MFMA16(af[mi], bfr[ni], acc[mi][ni]);
    }

    // C/D layout: col = lane&15, row = (lane>>4)*4 + reg   [verified m89/m91]
    const int r0 = (lane >> 4) * 4;
#pragma unroll
    for (int ni = 0; ni < 4; ++ni) {
        int col = n0 + wn * 64 + ni * 16 + l15;
        float bv = bias[col];
#pragma unroll
        for (int mi = 0; mi < 4; ++mi) {
#pragma unroll
            for (int i = 0; i < 4; ++i) {
                int row = m0 + wm * 64 + mi * 16 + r0 + i;
                float v = acc[mi][ni][i] + bv;
                size_t off = (size_t)row * N + col;
                if (OUT_F32) ((float*)Cout)[off] = v;
                else         ((__bf16*)Cout)[off] = (__bf16)v;
            }
        }
    }
}

// ---------------------------------------------------------------------------
// Flash attention over qkv[8192,3072] bf16. Per head h, row r of qkv holds
// q = [h*192, +64), k = [h*192+64, +64), v = [h*192+128, +64).
// Block: one (b,h), 64 q-rows; 4 waves, wave w owns q rows w*16..+16.
// Writes attention output in the reference's quirk reshape layout:
//   v2[b*2048 + h*128 + s/16][(s%16)*64 + hd]
__global__ __launch_bounds__(256) void attn_kernel(const __bf16* __restrict__ qkv,
                                                   __bf16* __restrict__ v2) {
    const int bh = blockIdx.y;
    const int b = bh >> 4, h = bh & 15;
    const int q0 = blockIdx.x * 64;
    const int lane = threadIdx.x & 63;
    const int wave = threadIdx.x >> 6;
    const int l15 = lane & 15;
    const int kg = (lane >> 4) * 8;
    const size_t rs = QKV_N;  // 3072
    const __bf16* base = qkv + (size_t)b * Sq * rs + (size_t)h * (3 * HDq);

    __shared__ __bf16 VT[64][72];  // V^T tile: [d][key]
    __shared__ __bf16 P[64][72];   // P tile (C-layout -> A-layout roundtrip)

    // Q fragments live in registers for the whole kernel.
    const int qrow = q0 + wave * 16 + l15;
    bf16x8 qa0 = *(const bf16x8*)(base + (size_t)qrow * rs + kg);
    bf16x8 qa1 = *(const bf16x8*)(base + (size_t)qrow * rs + 32 + kg);

    floatx4 o[4] = {};
    float m_i[4], l_i[4];
#pragma unroll
    for (int i = 0; i < 4; ++i) { m_i[i] = -1e30f; l_i[i] = 0.f; }

    for (int kt = 0; kt < Sq; kt += 64) {
        __syncthreads();
#pragma unroll
        for (int it = 0; it < 2; ++it) {
            int key = (threadIdx.x >> 3) + it * 32;
            int dg = (threadIdx.x & 7) * 8;
            bf16x8 vv = *(const bf16x8*)(base + (size_t)(kt + key) * rs + 2 * HDq + dg);
#pragma unroll
            for (int j = 0; j < 8; ++j) VT[dg + j][key] = vv[j];
        }
        __syncthreads();

        floatx4 s[4] = {};
#pragma unroll
        for (int t = 0; t < 4; ++t) {
            const __bf16* krow = base + (size_t)(kt + t * 16 + l15) * rs + HDq;
            bf16x8 b0 = *(const bf16x8*)(krow + kg);
            bf16x8 b1 = *(const bf16x8*)(krow + 32 + kg);
            s[t] = MFMA16(qa0, b0, s[t]);
            s[t] = MFMA16(qa1, b1, s[t]);
        }
#pragma unroll
        for (int t = 0; t < 4; ++t) s[t] *= 0.125f;

        float mx[4];
#pragma unroll
        for (int i = 0; i < 4; ++i)
            mx[i] = fmaxf(fmaxf(s[0][i], s[1][i]), fmaxf(s[2][i], s[3][i]));
#pragma unroll
        for (int m = 1; m < 16; m <<= 1) {
#pragma unroll
            for (int i = 0; i < 4; ++i) mx[i] = fmaxf(mx[i], __shfl_xor(mx[i], m));
        }

        float alpha[4], rsum[4];
#pragma unroll
        for (int i = 0; i < 4; ++i) {
            float mn = fmaxf(m_i[i], mx[i]);
            alpha[i] = __expf(m_i[i] - mn);
            m_i[i] = mn;
            rsum[i] = 0.f;
        }
#pragma unroll
        for (int t = 0; t < 4; ++t) {
#pragma unroll
            for (int i = 0; i < 4; ++i) {
                float p = __expf(s[t][i] - m_i[i]);
                s[t][i] = p;
                rsum[i] += p;
            }
        }
#pragma unroll
        for (int m = 1; m < 16; m <<= 1) {
#pragma unroll
            for (int i = 0; i < 4; ++i) rsum[i] += __shfl_xor(rsum[i], m);
        }
#pragma unroll
        for (int i = 0; i < 4; ++i) l_i[i] = l_i[i] * alpha[i] + rsum[i];

#pragma unroll
        for (int t = 0; t < 4; ++t) {
#pragma unroll
            for (int i = 0; i < 4; ++i) {
                o[t][i] *= alpha[i];
                P[wave * 16 + (lane >> 4) * 4 + i][t * 16 + l15] = (__bf16)s[t][i];
            }
        }

#pragma unroll
        for (int ks = 0; ks < 2; ++ks) {
            bf16x8 pa = *(const bf16x8*)(&P[wave * 16 + l15][ks * 32 + kg]);
#pragma unroll
            for (int t = 0; t < 4; ++t) {
                bf16x8 vb = *(const bf16x8*)(&VT[t * 16 + l15][ks * 32 + kg]);
                o[t] = MFMA16(pa, vb, o[t]);
            }
        }
    }

#pragma unroll
    for (int t = 0; t < 4; ++t) {
#pragma unroll
        for (int i = 0; i < 4; ++i) {
            int q = q0 + wave * 16 + (lane >> 4) * 4 + i;
            int d = t * 16 + l15;
            float val = o[t][i] / l_i[i];
            size_t row = (size_t)b * Sq + h * 128 + (q >> 4);
            size_t col = (size_t)(q & 15) * 64 + d;
            v2[row * Dq + col] = (__bf16)val;
        }
    }
}

// ---------------------------------------------------------------------------
extern "C" void kernel_launch(void* const* d_in, const int* in_sizes, int n_in,
                              void* d_out, int out_size, void* d_ws, size_t ws_size,
                              hipStream_t stream) {
    const float* x    = (const float*)d_in[0];  // [4,2048,1024]
    const float* Wqkv = (const float*)d_in[1];  // [1024,3072]
    const float* bqkv = (const float*)d_in[2];  // [3072]
    const float* Wo   = (const float*)d_in[3];  // [1024,1024]
    const float* bo   = (const float*)d_in[4];  // [1024]
    float* out = (float*)d_out;                 // [4,2048,1024] f32

    __bf16* xb    = (__bf16*)d_ws;                        // 8192*1024
    __bf16* WqkvT = xb    + (size_t)ROWS * Dq;            // 3072*1024
    __bf16* WoT   = WqkvT + (size_t)QKV_N * Dq;           // 1024*1024
    __bf16* qkvb  = WoT   + (size_t)Dq * Dq;              // 8192*3072
    __bf16* v2    = qkvb  + (size_t)ROWS * QKV_N;         // 8192*1024

    const int nx4 = ROWS * Dq / 4;
    cvt4_kernel<<<(nx4 + 255) / 256, 256, 0, stream>>>((const float4*)x, (bf16x4*)xb, nx4);
    tcvt_kernel<<<dim3(QKV_N / 32, Dq / 32), 256, 0, stream>>>(Wqkv, WqkvT, Dq, QKV_N);
    tcvt_kernel<<<dim3(Dq / 32, Dq / 32), 256, 0, stream>>>(Wo, WoT, Dq, Dq);

    gemm_bt_kernel<false><<<dim3(QKV_N / 128, ROWS / 128), 256, 0, stream>>>(
        xb, WqkvT, bqkv, (void*)qkvb, ROWS, QKV_N, Dq);

    attn_kernel<<<dim3(Sq / 64, Bq * Hq), 256, 0, stream>>>(qkvb, v2);

    gemm_bt_kernel<true><<<dim3(Dq / 128, ROWS / 128), 256, 0, stream>>>(
        v2, WoT, bo, (void*)out, ROWS, Dq, Dq);
}